// Round 1
// 902.983 us; speedup vs baseline: 1.0387x; 1.0387x over previous
//
#include <hip/hip_runtime.h>

#define BB 512
#define NPG 50
#define EPG 60
#define DD 128
#define VV 100000
#define VPAD 100032
#define NSPLITS 4
#define FSCALE 12.0f
#define NN (BB*NPG)        // 25600
#define EE (BB*EPG)        // 30720
#define NDTOT (NN*DD)      // 3276800
#define NCB (VPAD/64)      // 1563

typedef __attribute__((ext_vector_type(8))) short bfx8;
typedef __attribute__((ext_vector_type(4))) float f32x4;

__device__ __forceinline__ float sigmoidf_(float x){ return 1.f/(1.f+expf(-x)); }
__device__ __forceinline__ short f2bf(float f){
  union { float f; unsigned u; } v; v.f = f;
  unsigned r = v.u + 0x7FFF + ((v.u >> 16) & 1);
  return (short)(r >> 16);
}

// ---------- embn = l2norm(emb) in bf16, padded to VPAD rows ----------
__global__ __launch_bounds__(256) void k_embn(const float* __restrict__ emb, short* __restrict__ embn) {
  int row = blockIdx.x*4 + (threadIdx.x >> 6);
  int lane = threadIdx.x & 63;
  if (row >= VPAD) return;
  if (row >= VV) { embn[(size_t)row*DD+lane]=0; embn[(size_t)row*DD+64+lane]=0; return; }
  const float* r = emb + (size_t)row*DD;
  float a = r[lane], b = r[lane+64];
  float s = a*a + b*b;
  for (int off=32; off; off>>=1) s += __shfl_down(s, off);
  s = __shfl(s, 0);
  float inv = 1.0f/fmaxf(sqrtf(s), 1e-12f);
  embn[(size_t)row*DD+lane]    = f2bf(a*inv);
  embn[(size_t)row*DD+64+lane] = f2bf(b*inv);
}

// ---------- feat = l2norm(emb[iid]) -> x fp32 + xb bf16 ----------
__global__ __launch_bounds__(128) void k_gather(const int* __restrict__ iid, const float* __restrict__ emb,
                                                float* __restrict__ x, short* __restrict__ xb) {
  int n = blockIdx.x, d = threadIdx.x;
  int v = iid[n];
  float e = emb[(size_t)v*DD + d];
  __shared__ float red2[2];
  float ss = e*e;
  for (int off=32; off; off>>=1) ss += __shfl_down(ss, off);
  if ((d & 63)==0) red2[d>>6] = ss;
  __syncthreads();
  float inv = 1.f/fmaxf(sqrtf(red2[0]+red2[1]), 1e-12f);
  float f = e*inv;
  x[(size_t)n*DD + d] = f;
  xb[(size_t)n*DD + d] = f2bf(f);
}

// ---------- dt = max(edge_t)/SPLITS ----------
__global__ __launch_bounds__(256) void k_dt(const float* __restrict__ edge_t, float* __restrict__ dtp) {
  __shared__ float red[256];
  float m = -1e30f;
  for (int e = threadIdx.x; e < EE; e += 256) m = fmaxf(m, edge_t[e]);
  red[threadIdx.x] = m; __syncthreads();
  for (int s=128; s; s>>=1){ if ((int)threadIdx.x < s) red[threadIdx.x] = fmaxf(red[threadIdx.x], red[threadIdx.x+s]); __syncthreads(); }
  if (threadIdx.x==0) dtp[0] = red[0] / (float)NSPLITS;
}

// ---------- weight prep (bf16, [N][K] transposed layouts) ----------
__global__ void k_m12t(const float* __restrict__ W1, const float* __restrict__ W2,
                       const float* __restrict__ gw_ih, short* __restrict__ M12t) {
  int c = blockIdx.x, k = threadIdx.x;             // c<384, k<256
  const float* Wrow = (k < 128) ? (W1 + (size_t)k*128) : (W2 + (size_t)(k-128)*128);
  const float* grow = gw_ih + (size_t)c*256 + ((k < 128) ? 0 : 128);
  float s = 0.f;
  for (int j = 0; j < 128; ++j) s += Wrow[j]*grow[j];
  M12t[(size_t)c*256 + k] = f2bf(s);
}
__global__ void k_bfcopy(const float* __restrict__ src, short* __restrict__ dst) {
  size_t i = (size_t)blockIdx.x*blockDim.x + threadIdx.x;
  dst[i] = f2bf(src[i]);
}
__global__ void k_wrzt(const float* __restrict__ Wxr, const float* __restrict__ Wxz,
                       const float* __restrict__ Whr, const float* __restrict__ Whz,
                       short* __restrict__ Wrzt) {
  int c = blockIdx.x, k = threadIdx.x;             // 256 x 256
  float v;
  if (k < 128) v = (c < 128) ? Wxr[k*128+c] : Wxz[k*128+(c-128)];
  else         v = (c < 128) ? Whr[(k-128)*128+c] : Whz[(k-128)*128+(c-128)];
  Wrzt[(size_t)c*256 + k] = f2bf(v);
}
__global__ void k_wu2t(const float* __restrict__ Wxh, const float* __restrict__ Whh, short* __restrict__ Wu2t) {
  int c = blockIdx.x, k = threadIdx.x;             // 128 x 256
  float v = (k < 128) ? Wxh[k*128+c] : Whh[(k-128)*128+c];
  Wu2t[(size_t)c*256 + k] = f2bf(v);
}
__global__ void k_wt128(const float* __restrict__ W, short* __restrict__ Wt) {
  int c = blockIdx.x, k = threadIdx.x;             // 128 x 128
  Wt[(size_t)c*128 + k] = f2bf(W[(size_t)k*128 + c]);
}
__global__ void k_build_bias(const float* __restrict__ bxr, const float* __restrict__ bhr,
                             const float* __restrict__ bxz, const float* __restrict__ bhz,
                             const float* __restrict__ bxh, const float* __restrict__ bhh,
                             float* __restrict__ brz, float* __restrict__ bu) {
  int t = threadIdx.x;
  if (t < 128) brz[t] = bxr[t] + bhr[t];
  else if (t < 256) brz[t] = bxz[t-128] + bhz[t-128];
  else bu[t-256] = bxh[t-256] + bhh[t-256];
}

// ---------- per-group stage-C means -> ABb bf16 ----------
__global__ __launch_bounds__(128) void k_grp_mean1(const int* __restrict__ src, const int* __restrict__ dst,
                                                   const float* __restrict__ ew, const float* __restrict__ feat,
                                                   short* __restrict__ ABb) {
  __shared__ float fl[NPG*128];
  __shared__ float n1[NPG*128];
  __shared__ int sl[EPG], tl[EPG];
  __shared__ float wl[EPG];
  __shared__ float d1[NPG];
  int b = blockIdx.x, d = threadIdx.x;
  int nb = b*NPG, eb = b*EPG;
  for (int i = d; i < NPG*32; i += 128) {
    ((float4*)fl)[i] = ((const float4*)(feat + (size_t)nb*128))[i];
    ((float4*)n1)[i] = make_float4(0.f,0.f,0.f,0.f);
  }
  if (d < EPG) { sl[d] = src[eb+d]-nb; tl[d] = dst[eb+d]-nb; wl[d] = ew[eb+d]; }
  __syncthreads();
  for (int e = 0; e < EPG; ++e)
    n1[tl[e]*128+d] += fl[sl[e]*128+d]*wl[e];
  if (d < NPG) {
    float den = 0.f;
    for (int e = 0; e < EPG; ++e) den += (tl[e]==d) ? wl[e] : 0.f;
    d1[d] = (den == 0.f) ? 1.f : den;
  }
  __syncthreads();
  for (int n = 0; n < NPG; ++n)
    ABb[(size_t)(nb+n)*256 + d] = f2bf(n1[n*128+d]/d1[n]);
}
__global__ __launch_bounds__(128) void k_grp_mean2(const int* __restrict__ src, const int* __restrict__ dst,
                                                   const float* __restrict__ ew, const float* __restrict__ feat,
                                                   short* __restrict__ ABb) {
  __shared__ float fl[NPG*128];
  __shared__ float n2[NPG*128];
  __shared__ int sl[EPG], tl[EPG];
  __shared__ float wl[EPG];
  __shared__ float d2[NPG];
  int b = blockIdx.x, d = threadIdx.x;
  int nb = b*NPG, eb = b*EPG;
  for (int i = d; i < NPG*32; i += 128) {
    ((float4*)fl)[i] = ((const float4*)(feat + (size_t)nb*128))[i];
    ((float4*)n2)[i] = make_float4(0.f,0.f,0.f,0.f);
  }
  if (d < EPG) { sl[d] = src[eb+d]-nb; tl[d] = dst[eb+d]-nb; wl[d] = ew[eb+d]; }
  __syncthreads();
  for (int e = 0; e < EPG; ++e)
    n2[sl[e]*128+d] += fl[tl[e]*128+d]*wl[e];
  if (d < NPG) {
    float den = 0.f;
    for (int e = 0; e < EPG; ++e) den += (sl[e]==d) ? wl[e] : 0.f;
    d2[d] = (den == 0.f) ? 1.f : den;
  }
  __syncthreads();
  for (int n = 0; n < NPG; ++n)
    ABb[(size_t)(nb+n)*256 + 128 + d] = f2bf(n2[n*128+d]/d2[n]);
}

// ---------- GRU + l2norm ----------
__global__ __launch_bounds__(128) void k_gru(const float* __restrict__ gi, const float* __restrict__ gh,
                                             float* __restrict__ x, float* __restrict__ h) {
  int n = blockIdx.x, d = threadIdx.x;
  const float* gin = gi + (size_t)n*384;
  const float* ghn = gh + (size_t)n*384;
  float ir = gin[d], iz = gin[128+d], ig = gin[256+d];
  float hr = ghn[d], hz = ghn[128+d], hg = ghn[256+d];
  float f0 = x[(size_t)n*DD + d];
  float r = sigmoidf_(ir + hr);
  float z = sigmoidf_(iz + hz);
  float g = tanhf(ig + r*hg);
  float f = (1.f - z)*g + z*f0;
  __shared__ float red2[2];
  float ss = f*f;
  for (int off=32; off; off>>=1) ss += __shfl_down(ss, off);
  if ((d & 63)==0) red2[d>>6] = ss;
  __syncthreads();
  float inv = 1.f/fmaxf(sqrtf(red2[0]+red2[1]), 1e-12f);
  float out = f*inv;
  x[(size_t)n*DD + d] = out;
  h[(size_t)n*DD + d] = out;
}

// ---------- ODE per-group aggregations ----------
__global__ __launch_bounds__(128) void k_ode_agg1x(const int* __restrict__ src, const int* __restrict__ dst,
                                                   const float* __restrict__ edge_t, const float* __restrict__ node_t,
                                                   const float* __restrict__ dtp, int kstep,
                                                   const float* __restrict__ x, short* __restrict__ ABb,
                                                   float* __restrict__ dis_ws, float* __restrict__ emf_ws) {
  __shared__ float xl[NPG*128];
  __shared__ float ax[NPG*128];
  __shared__ int sl[EPG], tl[EPG];
  __shared__ float actl[EPG];
  __shared__ float disl[NPG];
  __shared__ float ntl[NPG];
  int b = blockIdx.x, d = threadIdx.x;
  int nb = b*NPG, eb = b*EPG;
  float t = (float)kstep * dtp[0];
  if (d < EPG) { sl[d] = src[eb+d]-nb; tl[d] = dst[eb+d]-nb; }
  if (d < NPG) ntl[d] = node_t[nb+d];
  for (int i = d; i < NPG*32; i += 128) {
    ((float4*)xl)[i] = ((const float4*)(x + (size_t)nb*128))[i];
    ((float4*)ax)[i] = make_float4(0.f,0.f,0.f,0.f);
  }
  __syncthreads();
  if (d < EPG) {
    int s = sl[d], tt = tl[d];
    float a = (edge_t[eb+d] <= t && ntl[s] >= t && ntl[tt] >= t && s != tt) ? 1.f : 0.f;
    actl[d] = a;
    emf_ws[eb+d] = a;
  }
  __syncthreads();
  if (d < NPG) {
    float deg = 0.f;
    for (int e = 0; e < EPG; ++e) deg += actl[e]*((sl[e]==d ? 1.f:0.f)+(tl[e]==d ? 1.f:0.f));
    disl[d] = rsqrtf(fmaxf(deg, 1.f));
    dis_ws[nb+d] = disl[d];
  }
  __syncthreads();
  for (int e = 0; e < EPG; ++e) {
    if (actl[e] != 0.f) {
      int s = sl[e], tt = tl[e];
      ax[tt*128+d] += xl[s*128+d]*disl[s];
      ax[s*128+d]  += xl[tt*128+d]*disl[tt];
    }
  }
  __syncthreads();
  for (int n = 0; n < NPG; ++n)
    ABb[(size_t)(nb+n)*256 + d] = f2bf(ax[n*128+d]*disl[n]);
}

__global__ __launch_bounds__(128) void k_ode_agg1h(const int* __restrict__ src, const int* __restrict__ dst,
                                                   const float* __restrict__ emf_ws, const float* __restrict__ dis_ws,
                                                   const float* __restrict__ h, short* __restrict__ ABb) {
  __shared__ float hl[NPG*128];
  __shared__ float ah[NPG*128];
  __shared__ int sl[EPG], tl[EPG];
  __shared__ float actl[EPG];
  __shared__ float disl[NPG];
  int b = blockIdx.x, d = threadIdx.x;
  int nb = b*NPG, eb = b*EPG;
  if (d < EPG) { sl[d] = src[eb+d]-nb; tl[d] = dst[eb+d]-nb; actl[d] = emf_ws[eb+d]; }
  if (d < NPG) disl[d] = dis_ws[nb+d];
  for (int i = d; i < NPG*32; i += 128) {
    ((float4*)hl)[i] = ((const float4*)(h + (size_t)nb*128))[i];
    ((float4*)ah)[i] = make_float4(0.f,0.f,0.f,0.f);
  }
  __syncthreads();
  for (int e = 0; e < EPG; ++e) {
    if (actl[e] != 0.f) {
      int s = sl[e], tt = tl[e];
      ah[tt*128+d] += hl[s*128+d]*disl[s];
      ah[s*128+d]  += hl[tt*128+d]*disl[tt];
    }
  }
  __syncthreads();
  for (int n = 0; n < NPG; ++n)
    ABb[(size_t)(nb+n)*256 + 128 + d] = f2bf(ah[n*128+d]*disl[n]);
}

__global__ __launch_bounds__(128) void k_ode_agg2(const int* __restrict__ src, const int* __restrict__ dst,
                                                  const float* __restrict__ emf_ws, const float* __restrict__ dis_ws,
                                                  const float* __restrict__ rh, short* __restrict__ ABb) {
  __shared__ float rl[NPG*128];
  __shared__ float ar[NPG*128];
  __shared__ int sl[EPG], tl[EPG];
  __shared__ float actl[EPG];
  __shared__ float disl[NPG];
  int b = blockIdx.x, d = threadIdx.x;
  int nb = b*NPG, eb = b*EPG;
  if (d < EPG) { sl[d] = src[eb+d]-nb; tl[d] = dst[eb+d]-nb; actl[d] = emf_ws[eb+d]; }
  if (d < NPG) disl[d] = dis_ws[nb+d];
  for (int i = d; i < NPG*32; i += 128) {
    ((float4*)rl)[i] = ((const float4*)(rh + (size_t)nb*128))[i];
    ((float4*)ar)[i] = make_float4(0.f,0.f,0.f,0.f);
  }
  __syncthreads();
  for (int e = 0; e < EPG; ++e) {
    if (actl[e] != 0.f) {
      int s = sl[e], tt = tl[e];
      ar[tt*128+d] += rl[s*128+d]*disl[s];
      ar[s*128+d]  += rl[tt*128+d]*disl[tt];
    }
  }
  __syncthreads();
  for (int n = 0; n < NPG; ++n)
    ABb[(size_t)(nb+n)*256 + 128 + d] = f2bf(ar[n*128+d]*disl[n]);
}

// ---------- bf16 MFMA GEMM: 64x64 block tile, 4 waves, 16x16x32 ----------
// A [M][K] bf16 (lda), Bt [N][K] bf16 (ldbt). modes:
// 0: C = A@B + bias (fp32, ldc)                       grid (colblk, rowblk)
// 2: s=sigmoid(acc+brz[c]); c<128: rh=s*h; else zb=s   grid (colblk, rowblk)
// 3: uu=tanh(acc+bu[c]); h += dt*(1-zb)*(uu-h)         grid (colblk, rowblk)
// 4: logits LSE pass: per-64col-block (max,sumexp) partials ONLY (no store)
//    grid (rowblk=8, colblk=NCB) -- row-blocks adjacent for B-tile L2 reuse
// 5: logits store pass: out[r][c] = acc - bias[r]  (bias = lse)
//    grid (rowblk=8, colblk=NCB)
__global__ __launch_bounds__(256) void gemm_mfma(
    const short* __restrict__ A, int lda,
    const short* __restrict__ Bt, int ldbt,
    const float* __restrict__ bias,
    float* __restrict__ C, int ldc,
    int K, int mode,
    float* __restrict__ rh, float* __restrict__ zb,
    float* __restrict__ hbuf,
    const float* __restrict__ node_t,
    const float* __restrict__ dtp, int kstep,
    float* __restrict__ outp, float* __restrict__ pmax, float* __restrict__ psum)
{
  __shared__ short As[64*40];
  __shared__ short Bs[64*40];
  const int tid = threadIdx.x;
  const int wave = tid >> 6, lane = tid & 63;
  const int wr = wave >> 1, wc = wave & 1;
  const int quad = lane >> 4, l16 = lane & 15;
  // modes >=4 use swapped grid: x = row block (8 of them, adjacent -> B tile L2 reuse)
  const int rb = (mode >= 4) ? blockIdx.x : blockIdx.y;
  const int cb = (mode >= 4) ? blockIdx.y : blockIdx.x;
  const int row0 = rb*64, col0 = cb*64;
  f32x4 acc[2][2] = {{{0.f,0.f,0.f,0.f},{0.f,0.f,0.f,0.f}},{{0.f,0.f,0.f,0.f},{0.f,0.f,0.f,0.f}}};
  const int sm = tid >> 2, skq = tid & 3;
  const short* Ap = A + (size_t)(row0+sm)*lda + skq*8;
  const short* Bp = Bt + (size_t)(col0+sm)*ldbt + skq*8;
  for (int k0 = 0; k0 < K; k0 += 32) {
    *(bfx8*)&As[sm*40 + skq*8] = *(const bfx8*)(Ap + k0);
    *(bfx8*)&Bs[sm*40 + skq*8] = *(const bfx8*)(Bp + k0);
    __syncthreads();
    bfx8 a0 = *(bfx8*)&As[(wr*32 + l16)*40 + quad*8];
    bfx8 a1 = *(bfx8*)&As[(wr*32 + 16 + l16)*40 + quad*8];
    bfx8 b0 = *(bfx8*)&Bs[(wc*32 + l16)*40 + quad*8];
    bfx8 b1 = *(bfx8*)&Bs[(wc*32 + 16 + l16)*40 + quad*8];
    acc[0][0] = __builtin_amdgcn_mfma_f32_16x16x32_bf16(a0, b0, acc[0][0], 0, 0, 0);
    acc[0][1] = __builtin_amdgcn_mfma_f32_16x16x32_bf16(a0, b1, acc[0][1], 0, 0, 0);
    acc[1][0] = __builtin_amdgcn_mfma_f32_16x16x32_bf16(a1, b0, acc[1][0], 0, 0, 0);
    acc[1][1] = __builtin_amdgcn_mfma_f32_16x16x32_bf16(a1, b1, acc[1][1], 0, 0, 0);
    __syncthreads();
  }

  if (mode == 0) {
#pragma unroll
    for (int i = 0; i < 2; ++i)
#pragma unroll
      for (int j = 0; j < 2; ++j) {
        int gc = col0 + wc*32 + j*16 + l16;
        float bb = bias ? bias[gc] : 0.f;
#pragma unroll
        for (int r = 0; r < 4; ++r) {
          int gr = row0 + wr*32 + i*16 + quad*4 + r;
          C[(size_t)gr*ldc + gc] = acc[i][j][r] + bb;
        }
      }
  } else if (mode == 2) {
#pragma unroll
    for (int i = 0; i < 2; ++i)
#pragma unroll
      for (int j = 0; j < 2; ++j) {
        int gc = col0 + wc*32 + j*16 + l16;
        float bb = bias[gc];
#pragma unroll
        for (int r = 0; r < 4; ++r) {
          int gr = row0 + wr*32 + i*16 + quad*4 + r;
          float s = sigmoidf_(acc[i][j][r] + bb);
          if (gc < 128) rh[(size_t)gr*128 + gc] = s * hbuf[(size_t)gr*128 + gc];
          else          zb[(size_t)gr*128 + gc - 128] = s;
        }
      }
  } else if (mode == 3) {
    float dtv = dtp[0];
    float tt = (float)kstep * dtv;
#pragma unroll
    for (int i = 0; i < 2; ++i)
#pragma unroll
      for (int j = 0; j < 2; ++j) {
        int gc = col0 + wc*32 + j*16 + l16;
        float bb = bias[gc];
#pragma unroll
        for (int r = 0; r < 4; ++r) {
          int gr = row0 + wr*32 + i*16 + quad*4 + r;
          if (node_t[gr] >= tt) {
            float hv = hbuf[(size_t)gr*128 + gc];
            float zv = zb[(size_t)gr*128 + gc];
            float uu = tanhf(acc[i][j][r] + bb);
            hbuf[(size_t)gr*128 + gc] = hv + dtv*(1.f - zv)*(uu - hv);
          }
        }
      }
  } else if (mode == 4) { // LSE partials only: max-reduce first, then sum(exp)
    __shared__ float pm[64][2], ps[64][2];
    int c0 = col0 + wc*32 + l16;
    int c1 = c0 + 16;
#pragma unroll
    for (int i = 0; i < 2; ++i) {
#pragma unroll
      for (int r = 0; r < 4; ++r) {
        int rloc = wr*32 + i*16 + quad*4 + r;
        float v0 = (c0 < VV) ? acc[i][0][r] : -1e30f;
        float v1 = (c1 < VV) ? acc[i][1][r] : -1e30f;
        float m = fmaxf(v0, v1);
#pragma unroll
        for (int off = 1; off < 16; off <<= 1) m = fmaxf(m, __shfl_xor(m, off));
        float s = expf(v0 - m) + expf(v1 - m);
#pragma unroll
        for (int off = 1; off < 16; off <<= 1) s += __shfl_xor(s, off);
        if (l16 == 0) { pm[rloc][wc] = m; ps[rloc][wc] = s; }
      }
    }
    __syncthreads();
    if (tid < 64) {
      float m0 = pm[tid][0], m1 = pm[tid][1];
      float s0 = ps[tid][0], s1 = ps[tid][1];
      float M = fmaxf(m0, m1);
      float S = s0*expf(m0 - M) + s1*expf(m1 - M);
      pmax[(size_t)(row0 + tid)*NCB + cb] = M;
      psum[(size_t)(row0 + tid)*NCB + cb] = S;
    }
  } else { // mode 5: out = acc - lse[row]   (bias = lse)
#pragma unroll
    for (int i = 0; i < 2; ++i) {
#pragma unroll
      for (int r = 0; r < 4; ++r) {
        int gr = row0 + wr*32 + i*16 + quad*4 + r;
        float l = bias[gr];
#pragma unroll
        for (int j = 0; j < 2; ++j) {
          int gc = col0 + wc*32 + j*16 + l16;
          if (gc < VV) outp[(size_t)gr*VV + gc] = acc[i][j][r] - l;
        }
      }
    }
  }
}

// ---------- row l2norm (h -> fb fp32 + fbb bf16) ----------
__global__ __launch_bounds__(128) void k_l2rows(const float* __restrict__ in, float* __restrict__ out,
                                                short* __restrict__ outb) {
  int n = blockIdx.x, d = threadIdx.x;
  float v = in[(size_t)n*DD + d];
  __shared__ float red2[2];
  float ss = v*v;
  for (int off=32; off; off>>=1) ss += __shfl_down(ss, off);
  if ((d & 63)==0) red2[d>>6] = ss;
  __syncthreads();
  float inv = 1.f/fmaxf(sqrtf(red2[0]+red2[1]), 1e-12f);
  float f = v*inv;
  out[(size_t)n*DD + d] = f;
  outb[(size_t)n*DD + d] = f2bf(f);
}

// ---------- attention readout + W_sr + l2norm -> srvb bf16 (pre-scaled) ----------
__global__ __launch_bounds__(128) void k_attn(const float* __restrict__ fb, const float* __restrict__ U,
                                              const float* __restrict__ lv, const float* __restrict__ We,
                                              const float* __restrict__ W_sr, short* __restrict__ srvb) {
  int b = blockIdx.x, d = threadIdx.x;
  __shared__ float sc[NPG];
  __shared__ float lastv[DD], srg[DD];
  __shared__ float red2[2];
  const float* Ub  = U  + (size_t)b*NPG*DD;
  const float* lvb = lv + (size_t)b*DD;
  if (d < 64) {
    for (int i=0;i<NPG;++i) {
      float e = We[d]   * sigmoidf_(Ub[i*DD + d]      + lvb[d]) +
                We[d+64]* sigmoidf_(Ub[i*DD + 64 + d] + lvb[d+64]);
      for (int off=32; off; off>>=1) e += __shfl_down(e, off);
      if (d==0) sc[i] = e;
    }
  }
  __syncthreads();
  if (d < 64) {
    float v = (d < NPG) ? sc[d] : -1e30f;
    float m = v;
    for (int off=1; off<64; off<<=1) m = fmaxf(m, __shfl_xor(m, off));
    float ex = (d < NPG) ? expf(v - m) : 0.f;
    float s = ex;
    for (int off=1; off<64; off<<=1) s += __shfl_xor(s, off);
    if (d < NPG) sc[d] = ex/s;
  }
  __syncthreads();
  const float* fbb = fb + (size_t)b*NPG*DD;
  float lastd = fbb[(NPG-1)*DD + d];
  float sg = 0.f;
  for (int i=0;i<NPG;++i) sg += fbb[i*DD + d]*sc[i];
  lastv[d] = lastd; srg[d] = sg;
  __syncthreads();
  float acc = 0.f;
  for (int k=0;k<DD;++k) acc += lastv[k]*W_sr[k*DD + d];
  for (int k=0;k<DD;++k) acc += srg[k]*W_sr[(DD+k)*DD + d];
  float ss = acc*acc;
  for (int off=32; off; off>>=1) ss += __shfl_down(ss, off);
  if ((d & 63)==0) red2[d>>6] = ss;
  __syncthreads();
  float inv = 1.f/fmaxf(sqrtf(red2[0]+red2[1]), 1e-12f);
  srvb[(size_t)b*DD + d] = f2bf(FSCALE*acc*inv);
}

__global__ __launch_bounds__(256) void k_lse(const float* __restrict__ pmax, const float* __restrict__ psum,
                                             float* __restrict__ lse) {
  int r = blockIdx.x, tid = threadIdx.x;
  float m = -1e30f, s = 0.f;
  for (int cb = tid; cb < NCB; cb += 256) {
    float m2 = pmax[(size_t)r*NCB + cb], s2 = psum[(size_t)r*NCB + cb];
    float M = fmaxf(m, m2);
    s = s*expf(m - M) + s2*expf(m2 - M);
    m = M;
  }
  __shared__ float ms[256], ssh[256];
  ms[tid] = m; ssh[tid] = s; __syncthreads();
  for (int st=128; st; st>>=1) {
    if (tid < st) {
      float m2 = ms[tid+st], s2 = ssh[tid+st];
      float M = fmaxf(ms[tid], m2);
      ssh[tid] = ssh[tid]*expf(ms[tid]-M) + s2*expf(m2-M);
      ms[tid] = M;
    }
    __syncthreads();
  }
  if (tid==0) lse[r] = ms[0] + logf(ssh[0]);
}

extern "C" void kernel_launch(void* const* d_in, const int* in_sizes, int n_in,
                              void* d_out, int out_size, void* d_ws, size_t ws_size,
                              hipStream_t stream) {
  (void)in_sizes; (void)n_in; (void)out_size; (void)ws_size;
  const int*   iid    = (const int*)  d_in[0];
  const int*   src    = (const int*)  d_in[1];
  const int*   dst    = (const int*)  d_in[2];
  const float* edge_w = (const float*)d_in[3];
  const float* edge_t = (const float*)d_in[4];
  const float* node_t = (const float*)d_in[5];
  const float* emb    = (const float*)d_in[6];
  const float* W1     = (const float*)d_in[7];
  const float* W2     = (const float*)d_in[8];
  const float* gw_ih  = (const float*)d_in[9];
  const float* gw_hh  = (const float*)d_in[10];
  const float* gb_ih  = (const float*)d_in[11];
  const float* gb_hh  = (const float*)d_in[12];
  const float* Wxr = (const float*)d_in[13]; const float* bxr = (const float*)d_in[14];
  const float* Wxz = (const float*)d_in[15]; const float* bxz = (const float*)d_in[16];
  const float* Wxh = (const float*)d_in[17]; const float* bxh = (const float*)d_in[18];
  const float* Whr = (const float*)d_in[19]; const float* bhr = (const float*)d_in[20];
  const float* Whz = (const float*)d_in[21]; const float* bhz = (const float*)d_in[22];
  const float* Whh = (const float*)d_in[23]; const float* bhh = (const float*)d_in[24];
  const float* Wu  = (const float*)d_in[25];
  const float* Wv  = (const float*)d_in[26]; const float* bv  = (const float*)d_in[27];
  const float* We  = (const float*)d_in[28];
  const float* W_sr= (const float*)d_in[29];

  float* ws  = (float*)d_ws;
  float* out = (float*)d_out;

  // ---- workspace layout (float units; shorts live in float-sized slots) ----
  short* embn = (short*)ws;                         // VPAD*128 shorts = 6,402,048 fl
  float* pmax = ws + 6402048;                       // 512*1563 = 800,256
  float* psum = pmax + 800256;                      // 800,256
  short* M12t = (short*)(psum + 800256);            // 384*256 sh = 49,152 fl
  short* gwhhb= (short*)(psum + 800256 + 49152);    // 384*128 sh = 24,576 fl
  short* Wrzt = (short*)(psum + 800256 + 73728);    // 256*256 sh = 32,768 fl
  short* Wu2t = (short*)(psum + 800256 + 106496);   // 128*256 sh = 16,384 fl
  short* Wut  = (short*)(psum + 800256 + 122880);   // 128*128 sh = 8,192 fl
  short* Wvt  = (short*)(psum + 800256 + 131072);   // 8,192 fl
  float* brz  = psum + 800256 + 139264;             // 256
  float* bu   = brz + 256;                          // 128
  float* lv   = bu + 128;                           // 65,536
  float* dis  = lv + 65536;                         // 25,600
  float* emf  = dis + 25600;                        // 30,720
  float* dtp  = emf + 30720;                        // 4
  float* lse  = dtp + 4;                            // 512

  // ---- d_out as scratch until the logits pass (51.2M floats) ----
  short* ABb = (short*)out;                         // 25600*256 sh (3.28M fl)
  float* x   = out + (size_t) 4*1024*1024;          // 3.28M
  float* h   = out + (size_t) 8*1024*1024;          // 3.28M
  float* rh  = out + (size_t)12*1024*1024;          // 3.28M
  float* zb  = out + (size_t)16*1024*1024;          // 3.28M
  float* gi  = out + (size_t)20*1024*1024;          // 9.83M
  float* gh  = out + (size_t)30*1024*1024;          // 9.83M
  float* U   = out + (size_t)20*1024*1024;          // reuse gi after GRU
  short* xb  = (short*)(out + (size_t)40*1024*1024);// 25600*128 sh (1.64M fl)
  short* fbb = (short*)(out + (size_t)42*1024*1024);// 1.64M fl

  // ---- prep ----
  k_embn<<<VPAD/4, 256, 0, stream>>>(emb, embn);
  k_gather<<<NN, 128, 0, stream>>>(iid, emb, x, xb);
  k_dt<<<1, 256, 0, stream>>>(edge_t, dtp);
  k_m12t<<<384, 256, 0, stream>>>(W1, W2, gw_ih, M12t);
  k_bfcopy<<<384, 128, 0, stream>>>(gw_hh, gwhhb);
  k_wrzt<<<256, 256, 0, stream>>>(Wxr, Wxz, Whr, Whz, Wrzt);
  k_wu2t<<<128, 256, 0, stream>>>(Wxh, Whh, Wu2t);
  k_wt128<<<128, 128, 0, stream>>>(Wu, Wut);
  k_wt128<<<128, 128, 0, stream>>>(Wv, Wvt);
  k_build_bias<<<1, 384, 0, stream>>>(bxr, bhr, bxz, bhz, bxh, bhh, brz, bu);

  // ---- stage C ----
  k_grp_mean1<<<BB, 128, 0, stream>>>(src, dst, edge_w, x, ABb);
  k_grp_mean2<<<BB, 128, 0, stream>>>(src, dst, edge_w, x, ABb);

  // ---- GRU ----
  gemm_mfma<<<dim3(6,400), 256, 0, stream>>>(ABb, 256, M12t, 256, gb_ih, gi, 384, 256, 0,
      nullptr, nullptr, nullptr, nullptr, nullptr, 0, nullptr, nullptr, nullptr);
  gemm_mfma<<<dim3(6,400), 256, 0, stream>>>(xb, 128, gwhhb, 128, gb_hh, gh, 384, 128, 0,
      nullptr, nullptr, nullptr, nullptr, nullptr, 0, nullptr, nullptr, nullptr);
  k_gru<<<NN, 128, 0, stream>>>(gi, gh, x, h);

  // ---- ODE ----
  for (int k = 0; k < NSPLITS; ++k) {
    k_ode_agg1x<<<BB, 128, 0, stream>>>(src, dst, edge_t, node_t, dtp, k, x, ABb, dis, emf);
    k_ode_agg1h<<<BB, 128, 0, stream>>>(src, dst, emf, dis, h, ABb);
    gemm_mfma<<<dim3(4,400), 256, 0, stream>>>(ABb, 256, Wrzt, 256, brz, nullptr, 0, 256, 2,
        rh, zb, h, nullptr, nullptr, 0, nullptr, nullptr, nullptr);
    k_ode_agg2<<<BB, 128, 0, stream>>>(src, dst, emf, dis, rh, ABb);
    gemm_mfma<<<dim3(2,400), 256, 0, stream>>>(ABb, 256, Wu2t, 256, bu, nullptr, 0, 256, 3,
        nullptr, zb, h, node_t, dtp, k, nullptr, nullptr, nullptr);
  }

  // ---- attention ----
  k_l2rows<<<NN, 128, 0, stream>>>(h, x, fbb);
  gemm_mfma<<<dim3(2,400), 256, 0, stream>>>(fbb, 128, Wut, 128, nullptr, U, 128, 128, 0,
      nullptr, nullptr, nullptr, nullptr, nullptr, 0, nullptr, nullptr, nullptr);
  gemm_mfma<<<dim3(2,8), 256, 0, stream>>>(fbb + (size_t)(NPG-1)*DD, NPG*DD, Wvt, 128, bv, lv, 128, 128, 0,
      nullptr, nullptr, nullptr, nullptr, nullptr, 0, nullptr, nullptr, nullptr);
  k_attn<<<BB, 128, 0, stream>>>(x, U, lv, We, W_sr, (short*)((float*)ws + 6402048 + 800256*2 + 139264 + 256 + 128 + 65536 + 25600 + 30720 + 4 + 512));

  short* srvb = (short*)((float*)ws + 6402048 + 800256*2 + 139264 + 256 + 128 + 65536 + 25600 + 30720 + 4 + 512);

  // ---- logits: pass 1 (LSE partials, no store) -> lse -> pass 2 (store acc - lse) ----
  gemm_mfma<<<dim3(8,NCB), 256, 0, stream>>>(srvb, 128, embn, 128, nullptr, nullptr, 0, 128, 4,
      nullptr, nullptr, nullptr, nullptr, nullptr, 0, nullptr, pmax, psum);
  k_lse<<<BB, 256, 0, stream>>>(pmax, psum, lse);
  gemm_mfma<<<dim3(8,NCB), 256, 0, stream>>>(srvb, 128, embn, 128, lse, nullptr, 0, 128, 5,
      nullptr, nullptr, nullptr, nullptr, nullptr, 0, out, nullptr, nullptr);
}

// Round 2
// 813.513 us; speedup vs baseline: 1.1529x; 1.1100x over previous
//
#include <hip/hip_runtime.h>

#define BB 512
#define NPG 50
#define EPG 60
#define DD 128
#define VV 100000
#define VPAD 100032
#define NSPLITS 4
#define FSCALE 12.0f
#define NN (BB*NPG)        // 25600
#define EE (BB*EPG)        // 30720
#define NDTOT (NN*DD)      // 3276800
#define NCB (VPAD/64)      // 1563

typedef __attribute__((ext_vector_type(8))) short bfx8;
typedef __attribute__((ext_vector_type(4))) float f32x4;

__device__ __forceinline__ float sigmoidf_(float x){ return 1.f/(1.f+expf(-x)); }
__device__ __forceinline__ short f2bf(float f){
  union { float f; unsigned u; } v; v.f = f;
  unsigned r = v.u + 0x7FFF + ((v.u >> 16) & 1);
  return (short)(r >> 16);
}

// ---------- embn = l2norm(emb) in bf16, padded to VPAD rows ----------
__global__ __launch_bounds__(256) void k_embn(const float* __restrict__ emb, short* __restrict__ embn) {
  int row = blockIdx.x*4 + (threadIdx.x >> 6);
  int lane = threadIdx.x & 63;
  if (row >= VPAD) return;
  if (row >= VV) { embn[(size_t)row*DD+lane]=0; embn[(size_t)row*DD+64+lane]=0; return; }
  const float* r = emb + (size_t)row*DD;
  float a = r[lane], b = r[lane+64];
  float s = a*a + b*b;
  for (int off=32; off; off>>=1) s += __shfl_down(s, off);
  s = __shfl(s, 0);
  float inv = 1.0f/fmaxf(sqrtf(s), 1e-12f);
  embn[(size_t)row*DD+lane]    = f2bf(a*inv);
  embn[(size_t)row*DD+64+lane] = f2bf(b*inv);
}

// ---------- feat = l2norm(emb[iid]) -> x fp32 + xb bf16 ----------
__global__ __launch_bounds__(128) void k_gather(const int* __restrict__ iid, const float* __restrict__ emb,
                                                float* __restrict__ x, short* __restrict__ xb) {
  int n = blockIdx.x, d = threadIdx.x;
  int v = iid[n];
  float e = emb[(size_t)v*DD + d];
  __shared__ float red2[2];
  float ss = e*e;
  for (int off=32; off; off>>=1) ss += __shfl_down(ss, off);
  if ((d & 63)==0) red2[d>>6] = ss;
  __syncthreads();
  float inv = 1.f/fmaxf(sqrtf(red2[0]+red2[1]), 1e-12f);
  float f = e*inv;
  x[(size_t)n*DD + d] = f;
  xb[(size_t)n*DD + d] = f2bf(f);
}

// ---------- dt = max(edge_t)/SPLITS ----------
__global__ __launch_bounds__(256) void k_dt(const float* __restrict__ edge_t, float* __restrict__ dtp) {
  __shared__ float red[256];
  float m = -1e30f;
  for (int e = threadIdx.x; e < EE; e += 256) m = fmaxf(m, edge_t[e]);
  red[threadIdx.x] = m; __syncthreads();
  for (int s=128; s; s>>=1){ if ((int)threadIdx.x < s) red[threadIdx.x] = fmaxf(red[threadIdx.x], red[threadIdx.x+s]); __syncthreads(); }
  if (threadIdx.x==0) dtp[0] = red[0] / (float)NSPLITS;
}

// ---------- weight prep (bf16, [N][K] transposed layouts) ----------
__global__ void k_m12t(const float* __restrict__ W1, const float* __restrict__ W2,
                       const float* __restrict__ gw_ih, short* __restrict__ M12t) {
  int c = blockIdx.x, k = threadIdx.x;             // c<384, k<256
  const float* Wrow = (k < 128) ? (W1 + (size_t)k*128) : (W2 + (size_t)(k-128)*128);
  const float* grow = gw_ih + (size_t)c*256 + ((k < 128) ? 0 : 128);
  float s = 0.f;
  for (int j = 0; j < 128; ++j) s += Wrow[j]*grow[j];
  M12t[(size_t)c*256 + k] = f2bf(s);
}
__global__ void k_bfcopy(const float* __restrict__ src, short* __restrict__ dst) {
  size_t i = (size_t)blockIdx.x*blockDim.x + threadIdx.x;
  dst[i] = f2bf(src[i]);
}
__global__ void k_wrzt(const float* __restrict__ Wxr, const float* __restrict__ Wxz,
                       const float* __restrict__ Whr, const float* __restrict__ Whz,
                       short* __restrict__ Wrzt) {
  int c = blockIdx.x, k = threadIdx.x;             // 256 x 256
  float v;
  if (k < 128) v = (c < 128) ? Wxr[k*128+c] : Wxz[k*128+(c-128)];
  else         v = (c < 128) ? Whr[(k-128)*128+c] : Whz[(k-128)*128+(c-128)];
  Wrzt[(size_t)c*256 + k] = f2bf(v);
}
__global__ void k_wu2t(const float* __restrict__ Wxh, const float* __restrict__ Whh, short* __restrict__ Wu2t) {
  int c = blockIdx.x, k = threadIdx.x;             // 128 x 256
  float v = (k < 128) ? Wxh[k*128+c] : Whh[(k-128)*128+c];
  Wu2t[(size_t)c*256 + k] = f2bf(v);
}
__global__ void k_wt128(const float* __restrict__ W, short* __restrict__ Wt) {
  int c = blockIdx.x, k = threadIdx.x;             // 128 x 128
  Wt[(size_t)c*128 + k] = f2bf(W[(size_t)k*128 + c]);
}
__global__ void k_build_bias(const float* __restrict__ bxr, const float* __restrict__ bhr,
                             const float* __restrict__ bxz, const float* __restrict__ bhz,
                             const float* __restrict__ bxh, const float* __restrict__ bhh,
                             float* __restrict__ brz, float* __restrict__ bu) {
  int t = threadIdx.x;
  if (t < 128) brz[t] = bxr[t] + bhr[t];
  else if (t < 256) brz[t] = bxz[t-128] + bhz[t-128];
  else bu[t-256] = bxh[t-256] + bhh[t-256];
}

// ---------- per-group stage-C means (both directions) -> ABb bf16 ----------
__global__ __launch_bounds__(256) void k_grp_mean(const int* __restrict__ src, const int* __restrict__ dst,
                                                  const float* __restrict__ ew, const float* __restrict__ feat,
                                                  short* __restrict__ ABb) {
  __shared__ float fl[NPG*128];
  __shared__ float n1[NPG*128];
  __shared__ float n2[NPG*128];
  __shared__ int sl[EPG], tl[EPG];
  __shared__ float wl[EPG];
  __shared__ float d1[NPG], d2[NPG];
  int b = blockIdx.x, tid = threadIdx.x;
  int nb = b*NPG, eb = b*EPG;
  for (int i = tid; i < NPG*32; i += 256) {
    ((float4*)fl)[i] = ((const float4*)(feat + (size_t)nb*128))[i];
    ((float4*)n1)[i] = make_float4(0.f,0.f,0.f,0.f);
    ((float4*)n2)[i] = make_float4(0.f,0.f,0.f,0.f);
  }
  if (tid < EPG) { sl[tid] = src[eb+tid]-nb; tl[tid] = dst[eb+tid]-nb; wl[tid] = ew[eb+tid]; }
  __syncthreads();
  const int dgrp = tid >> 7, d = tid & 127;
  if (dgrp == 0) {
    for (int e = 0; e < EPG; ++e) n1[tl[e]*128+d] += fl[sl[e]*128+d]*wl[e];
  } else {
    for (int e = 0; e < EPG; ++e) n2[sl[e]*128+d] += fl[tl[e]*128+d]*wl[e];
  }
  if (tid < NPG) {
    float den = 0.f;
    for (int e = 0; e < EPG; ++e) den += (tl[e]==tid) ? wl[e] : 0.f;
    d1[tid] = (den == 0.f) ? 1.f : den;
  } else if (tid >= 128 && tid < 128+NPG) {
    int dd = tid - 128;
    float den = 0.f;
    for (int e = 0; e < EPG; ++e) den += (sl[e]==dd) ? wl[e] : 0.f;
    d2[dd] = (den == 0.f) ? 1.f : den;
  }
  __syncthreads();
  for (int n = 0; n < NPG; ++n) {
    float v = dgrp ? (n2[n*128+d]/d2[n]) : (n1[n*128+d]/d1[n]);
    ABb[(size_t)(nb+n)*256 + dgrp*128 + d] = f2bf(v);
  }
}

// ---------- GRU + l2norm (writes x only; h starts equal to x in ODE) ----------
__global__ __launch_bounds__(128) void k_gru(const float* __restrict__ gi, const float* __restrict__ gh,
                                             float* __restrict__ x) {
  int n = blockIdx.x, d = threadIdx.x;
  const float* gin = gi + (size_t)n*384;
  const float* ghn = gh + (size_t)n*384;
  float ir = gin[d], iz = gin[128+d], ig = gin[256+d];
  float hr = ghn[d], hz = ghn[128+d], hg = ghn[256+d];
  float f0 = x[(size_t)n*DD + d];
  float r = sigmoidf_(ir + hr);
  float z = sigmoidf_(iz + hz);
  float g = tanhf(ig + r*hg);
  float f = (1.f - z)*g + z*f0;
  __shared__ float red2[2];
  float ss = f*f;
  for (int off=32; off; off>>=1) ss += __shfl_down(ss, off);
  if ((d & 63)==0) red2[d>>6] = ss;
  __syncthreads();
  float inv = 1.f/fmaxf(sqrtf(red2[0]+red2[1]), 1e-12f);
  x[(size_t)n*DD + d] = f*inv;
}

// ---------- fused ODE: all 4 splits per group entirely in LDS ----------
// in : x (post-GRU feat, fp32), edges, Wrzt[256][256] bf16, Wu2t[128][256] bf16, brz, bu
// out: x <- l2norm(h_final) fp32, fbb <- bf16 of same
__global__ __launch_bounds__(256) void k_ode_fused(
    const int* __restrict__ src, const int* __restrict__ dst,
    const float* __restrict__ edge_t, const float* __restrict__ node_t,
    const float* __restrict__ dtp,
    float* __restrict__ x, short* __restrict__ fbb,
    const short* __restrict__ Wrzt, const short* __restrict__ Wu2t,
    const float* __restrict__ brz, const float* __restrict__ bu)
{
  __shared__ __align__(16) float xl[NPG*128];   // 25.6 KB (persist)
  __shared__ __align__(16) float hl[NPG*128];   // 25.6 KB (persist)
  __shared__ __align__(16) float S1[NPG*128];   // agg_x scratch; then rh
  __shared__ __align__(16) float S2[NPG*128];   // agg_h scratch; then agg_rh
  __shared__ __align__(16) float zzl[NPG*128];  // z gate
  __shared__ __align__(16) short aggX[64*136];  // A left  half (k 0..127), 17.4 KB
  __shared__ __align__(16) short aggH[64*136];  // A right half (k 128..255)
  __shared__ int stl[EPG];                      // s | t<<16
  __shared__ float etl[EPG];
  __shared__ float ntl[NPG];
  __shared__ float disl[NPG];
  __shared__ unsigned long long actm_s;
  __shared__ float red4[4];

  const int b = blockIdx.x, tid = threadIdx.x;
  const int nb = b*NPG, eb = b*EPG;
  const int wave = tid>>6, lane = tid&63, quad = lane>>4, l16 = lane&15;
  const float dtv = dtp[0];

  for (int i = tid; i < NPG*32; i += 256) {
    float4 v = ((const float4*)(x + (size_t)nb*128))[i];
    ((float4*)xl)[i] = v;
    ((float4*)hl)[i] = v;
  }
  if (tid < EPG) { stl[tid] = (src[eb+tid]-nb) | ((dst[eb+tid]-nb)<<16); etl[tid] = edge_t[eb+tid]; }
  if (tid >= 64 && tid < 64+NPG) ntl[tid-64] = node_t[nb+tid-64];
  for (int i = tid; i < 14*136; i += 256) { aggX[50*136 + i] = 0; aggH[50*136 + i] = 0; }
  __syncthreads();

  for (int ks = 0; ks < NSPLITS; ++ks) {
    const float t = (float)ks * dtv;
    // --- edge activity mask (wave 0, 64-bit ballot) ---
    if (wave == 0) {
      bool p = false;
      if (lane < EPG) {
        int st = stl[lane]; int s = st & 0xffff, tt = st >> 16;
        p = (etl[lane] <= t) && (ntl[s] >= t) && (ntl[tt] >= t) && (s != tt);
      }
      unsigned long long m = __ballot(p);
      if (lane == 0) actm_s = m;
    }
    for (int i = tid; i < NPG*128; i += 256) { S1[i] = 0.f; S2[i] = 0.f; }
    __syncthreads();
    const unsigned long long actm = actm_s;
    if (tid < NPG) {
      float deg = 0.f;
      for (int e = 0; e < EPG; ++e) {
        if ((actm >> e) & 1ULL) {
          int st = stl[e]; int s = st & 0xffff, tt = st >> 16;
          deg += (s==tid ? 1.f:0.f) + (tt==tid ? 1.f:0.f);
        }
      }
      disl[tid] = rsqrtf(fmaxf(deg, 1.f));
    }
    __syncthreads();
    // --- agg_x -> S1, agg_h -> S2 (threads 0-127, both directions serial) ---
    if (tid < 128) {
      const int d = tid;
      for (int e = 0; e < EPG; ++e) {
        if ((actm >> e) & 1ULL) {
          int st = stl[e]; int s = st & 0xffff, tt = st >> 16;
          float ds_ = disl[s], dt_ = disl[tt];
          S1[tt*128+d] += xl[s*128+d]*ds_;
          S1[s*128+d]  += xl[tt*128+d]*dt_;
          S2[tt*128+d] += hl[s*128+d]*ds_;
          S2[s*128+d]  += hl[tt*128+d]*dt_;
        }
      }
    }
    __syncthreads();
    for (int i = tid; i < NPG*128; i += 256) {
      int r = i >> 7, c = i & 127;
      aggX[r*136 + c] = f2bf(S1[i]*disl[r]);
      aggH[r*136 + c] = f2bf(S2[i]*disl[r]);
    }
    __syncthreads();
    // --- GEMM1: C[64][256] = [aggX|aggH] @ Wrzt^T ; epilogue rh->S1, zz->zzl ---
    {
      f32x4 acc[4][4] = {{{0.f,0.f,0.f,0.f},{0.f,0.f,0.f,0.f},{0.f,0.f,0.f,0.f},{0.f,0.f,0.f,0.f}},
                         {{0.f,0.f,0.f,0.f},{0.f,0.f,0.f,0.f},{0.f,0.f,0.f,0.f},{0.f,0.f,0.f,0.f}},
                         {{0.f,0.f,0.f,0.f},{0.f,0.f,0.f,0.f},{0.f,0.f,0.f,0.f},{0.f,0.f,0.f,0.f}},
                         {{0.f,0.f,0.f,0.f},{0.f,0.f,0.f,0.f},{0.f,0.f,0.f,0.f},{0.f,0.f,0.f,0.f}}};
      for (int k0 = 0; k0 < 256; k0 += 32) {
        const short* Ab = (k0 < 128) ? aggX : aggH;
        const int kk = (k0 & 127) + quad*8;
        bfx8 af[4];
#pragma unroll
        for (int m = 0; m < 4; ++m) af[m] = *(const bfx8*)&Ab[(m*16+l16)*136 + kk];
#pragma unroll
        for (int n = 0; n < 4; ++n) {
          const int bn = (wave*4+n)*16 + l16;
          bfx8 bf = *(const bfx8*)&Wrzt[(size_t)bn*256 + k0 + quad*8];
#pragma unroll
          for (int m = 0; m < 4; ++m)
            acc[m][n] = __builtin_amdgcn_mfma_f32_16x16x32_bf16(af[m], bf, acc[m][n], 0, 0, 0);
        }
      }
#pragma unroll
      for (int n = 0; n < 4; ++n) {
        const int col = (wave*4+n)*16 + l16;
        const float bb = brz[col];
#pragma unroll
        for (int m = 0; m < 4; ++m)
#pragma unroll
          for (int r = 0; r < 4; ++r) {
            const int row = m*16 + quad*4 + r;
            if (row < NPG) {
              float s = sigmoidf_(acc[m][n][r] + bb);
              if (col < 128) S1[row*128+col] = s * hl[row*128+col];   // rh
              else           zzl[row*128+col-128] = s;                // zz
            }
          }
      }
    }
    __syncthreads();
    // --- agg_rh -> S2 ---
    for (int i = tid; i < NPG*128; i += 256) S2[i] = 0.f;
    __syncthreads();
    if (tid < 128) {
      const int d = tid;
      for (int e = 0; e < EPG; ++e) {
        if ((actm >> e) & 1ULL) {
          int st = stl[e]; int s = st & 0xffff, tt = st >> 16;
          S2[tt*128+d] += S1[s*128+d]*disl[s];
          S2[s*128+d]  += S1[tt*128+d]*disl[tt];
        }
      }
    }
    __syncthreads();
    for (int i = tid; i < NPG*128; i += 256) {
      int r = i >> 7, c = i & 127;
      aggH[r*136 + c] = f2bf(S2[i]*disl[r]);
    }
    __syncthreads();
    // --- GEMM2: C[64][128] = [aggX|aggH] @ Wu2t^T ; epilogue h update ---
    {
      f32x4 acc[4][2] = {{{0.f,0.f,0.f,0.f},{0.f,0.f,0.f,0.f}},
                         {{0.f,0.f,0.f,0.f},{0.f,0.f,0.f,0.f}},
                         {{0.f,0.f,0.f,0.f},{0.f,0.f,0.f,0.f}},
                         {{0.f,0.f,0.f,0.f},{0.f,0.f,0.f,0.f}}};
      for (int k0 = 0; k0 < 256; k0 += 32) {
        const short* Ab = (k0 < 128) ? aggX : aggH;
        const int kk = (k0 & 127) + quad*8;
        bfx8 af[4];
#pragma unroll
        for (int m = 0; m < 4; ++m) af[m] = *(const bfx8*)&Ab[(m*16+l16)*136 + kk];
#pragma unroll
        for (int n = 0; n < 2; ++n) {
          const int bn = (wave*2+n)*16 + l16;
          bfx8 bf = *(const bfx8*)&Wu2t[(size_t)bn*256 + k0 + quad*8];
#pragma unroll
          for (int m = 0; m < 4; ++m)
            acc[m][n] = __builtin_amdgcn_mfma_f32_16x16x32_bf16(af[m], bf, acc[m][n], 0, 0, 0);
        }
      }
#pragma unroll
      for (int n = 0; n < 2; ++n) {
        const int col = (wave*2+n)*16 + l16;
        const float bb = bu[col];
#pragma unroll
        for (int m = 0; m < 4; ++m)
#pragma unroll
          for (int r = 0; r < 4; ++r) {
            const int row = m*16 + quad*4 + r;
            if (row < NPG && ntl[row] >= t) {
              float hv = hl[row*128+col];
              float uu = tanhf(acc[m][n][r] + bb);
              float zv = zzl[row*128+col];
              hl[row*128+col] = hv + dtv*(1.f - zv)*(uu - hv);
            }
          }
      }
    }
    __syncthreads();
  }

  // --- final l2norm of h -> x (fp32) + fbb (bf16), 2 rows at a time ---
  for (int rp = 0; rp < NPG; rp += 2) {
    const int r = rp + (tid>>7);
    const int d = tid & 127;
    float v = hl[r*128 + d];
    float ss = v*v;
    for (int off=32; off; off>>=1) ss += __shfl_down(ss, off);
    if (lane == 0) red4[wave] = ss;
    __syncthreads();
    int w0 = (tid>>7)*2;
    float inv = 1.f/fmaxf(sqrtf(red4[w0]+red4[w0+1]), 1e-12f);
    float f = v*inv;
    x[(size_t)(nb+r)*128 + d] = f;
    fbb[(size_t)(nb+r)*128 + d] = f2bf(f);
    __syncthreads();
  }
}

// ---------- bf16 MFMA GEMM: 64x64 block tile, 4 waves, 16x16x32 ----------
// A [M][K] bf16 (lda), Bt [N][K] bf16 (ldbt). modes:
// 0: C = A@B + bias (fp32, ldc)                        grid (colblk, rowblk)
// 4: logits LSE pass: per-64col-block (max,sumexp) partials only (no store)
//    grid (12504 linear, XCD-swizzled so one XCD owns all 8 rowblks of a cb)
// 5: logits store pass: out[r][c] = acc - bias[r]  (bias = lse); same grid
__global__ __launch_bounds__(256) void gemm_mfma(
    const short* __restrict__ A, int lda,
    const short* __restrict__ Bt, int ldbt,
    const float* __restrict__ bias,
    float* __restrict__ C, int ldc,
    int K, int mode,
    float* __restrict__ outp, float* __restrict__ pmax, float* __restrict__ psum)
{
  __shared__ short As[64*40];
  __shared__ short Bs[64*40];
  const int tid = threadIdx.x;
  const int wave = tid >> 6, lane = tid & 63;
  const int wr = wave >> 1, wc = wave & 1;
  const int quad = lane >> 4, l16 = lane & 15;
  int rb, cb;
  if (mode >= 4) {
    // bijective XCD swizzle: xcd = bid%8 gets contiguous cb range, rb fastest
    int t = (blockIdx.x & 7)*1563 + (blockIdx.x >> 3);   // 12504 = 8*1563
    rb = t & 7; cb = t >> 3;
  } else { rb = blockIdx.y; cb = blockIdx.x; }
  const int row0 = rb*64, col0 = cb*64;
  f32x4 acc[2][2] = {{{0.f,0.f,0.f,0.f},{0.f,0.f,0.f,0.f}},{{0.f,0.f,0.f,0.f},{0.f,0.f,0.f,0.f}}};
  const int sm = tid >> 2, skq = tid & 3;
  const short* Ap = A + (size_t)(row0+sm)*lda + skq*8;
  const short* Bp = Bt + (size_t)(col0+sm)*ldbt + skq*8;
  for (int k0 = 0; k0 < K; k0 += 32) {
    *(bfx8*)&As[sm*40 + skq*8] = *(const bfx8*)(Ap + k0);
    *(bfx8*)&Bs[sm*40 + skq*8] = *(const bfx8*)(Bp + k0);
    __syncthreads();
    bfx8 a0 = *(bfx8*)&As[(wr*32 + l16)*40 + quad*8];
    bfx8 a1 = *(bfx8*)&As[(wr*32 + 16 + l16)*40 + quad*8];
    bfx8 b0 = *(bfx8*)&Bs[(wc*32 + l16)*40 + quad*8];
    bfx8 b1 = *(bfx8*)&Bs[(wc*32 + 16 + l16)*40 + quad*8];
    acc[0][0] = __builtin_amdgcn_mfma_f32_16x16x32_bf16(a0, b0, acc[0][0], 0, 0, 0);
    acc[0][1] = __builtin_amdgcn_mfma_f32_16x16x32_bf16(a0, b1, acc[0][1], 0, 0, 0);
    acc[1][0] = __builtin_amdgcn_mfma_f32_16x16x32_bf16(a1, b0, acc[1][0], 0, 0, 0);
    acc[1][1] = __builtin_amdgcn_mfma_f32_16x16x32_bf16(a1, b1, acc[1][1], 0, 0, 0);
    __syncthreads();
  }

  if (mode == 0) {
#pragma unroll
    for (int i = 0; i < 2; ++i)
#pragma unroll
      for (int j = 0; j < 2; ++j) {
        int gc = col0 + wc*32 + j*16 + l16;
        float bb = bias ? bias[gc] : 0.f;
#pragma unroll
        for (int r = 0; r < 4; ++r) {
          int gr = row0 + wr*32 + i*16 + quad*4 + r;
          C[(size_t)gr*ldc + gc] = acc[i][j][r] + bb;
        }
      }
  } else if (mode == 4) { // LSE partials: max-reduce first, then sum(exp)
    __shared__ float pm[64][2], ps[64][2];
    int c0 = col0 + wc*32 + l16;
    int c1 = c0 + 16;
#pragma unroll
    for (int i = 0; i < 2; ++i) {
#pragma unroll
      for (int r = 0; r < 4; ++r) {
        int rloc = wr*32 + i*16 + quad*4 + r;
        float v0 = (c0 < VV) ? acc[i][0][r] : -1e30f;
        float v1 = (c1 < VV) ? acc[i][1][r] : -1e30f;
        float m = fmaxf(v0, v1);
#pragma unroll
        for (int off = 1; off < 16; off <<= 1) m = fmaxf(m, __shfl_xor(m, off));
        float s = expf(v0 - m) + expf(v1 - m);
#pragma unroll
        for (int off = 1; off < 16; off <<= 1) s += __shfl_xor(s, off);
        if (l16 == 0) { pm[rloc][wc] = m; ps[rloc][wc] = s; }
      }
    }
    __syncthreads();
    if (tid < 64) {
      float m0 = pm[tid][0], m1 = pm[tid][1];
      float s0 = ps[tid][0], s1 = ps[tid][1];
      float M = fmaxf(m0, m1);
      float S = s0*expf(m0 - M) + s1*expf(m1 - M);
      pmax[(size_t)(row0 + tid)*NCB + cb] = M;
      psum[(size_t)(row0 + tid)*NCB + cb] = S;
    }
  } else { // mode 5: out = acc - lse[row]   (bias = lse)
#pragma unroll
    for (int i = 0; i < 2; ++i) {
#pragma unroll
      for (int r = 0; r < 4; ++r) {
        int gr = row0 + wr*32 + i*16 + quad*4 + r;
        float l = bias[gr];
#pragma unroll
        for (int j = 0; j < 2; ++j) {
          int gc = col0 + wc*32 + j*16 + l16;
          if (gc < VV) outp[(size_t)gr*VV + gc] = acc[i][j][r] - l;
        }
      }
    }
  }
}

// ---------- attention readout + W_sr + l2norm -> srvb bf16 (pre-scaled) ----------
__global__ __launch_bounds__(128) void k_attn(const float* __restrict__ fb, const float* __restrict__ U,
                                              const float* __restrict__ lv, const float* __restrict__ We,
                                              const float* __restrict__ W_sr, short* __restrict__ srvb) {
  int b = blockIdx.x, d = threadIdx.x;
  __shared__ float sc[NPG];
  __shared__ float lastv[DD], srg[DD];
  __shared__ float red2[2];
  const float* Ub  = U  + (size_t)b*NPG*DD;
  const float* lvb = lv + (size_t)b*DD;
  if (d < 64) {
    for (int i=0;i<NPG;++i) {
      float e = We[d]   * sigmoidf_(Ub[i*DD + d]      + lvb[d]) +
                We[d+64]* sigmoidf_(Ub[i*DD + 64 + d] + lvb[d+64]);
      for (int off=32; off; off>>=1) e += __shfl_down(e, off);
      if (d==0) sc[i] = e;
    }
  }
  __syncthreads();
  if (d < 64) {
    float v = (d < NPG) ? sc[d] : -1e30f;
    float m = v;
    for (int off=1; off<64; off<<=1) m = fmaxf(m, __shfl_xor(m, off));
    float ex = (d < NPG) ? expf(v - m) : 0.f;
    float s = ex;
    for (int off=1; off<64; off<<=1) s += __shfl_xor(s, off);
    if (d < NPG) sc[d] = ex/s;
  }
  __syncthreads();
  const float* fbb = fb + (size_t)b*NPG*DD;
  float lastd = fbb[(NPG-1)*DD + d];
  float sg = 0.f;
  for (int i=0;i<NPG;++i) sg += fbb[i*DD + d]*sc[i];
  lastv[d] = lastd; srg[d] = sg;
  __syncthreads();
  float acc = 0.f;
  for (int k=0;k<DD;++k) acc += lastv[k]*W_sr[k*DD + d];
  for (int k=0;k<DD;++k) acc += srg[k]*W_sr[(DD+k)*DD + d];
  float ss = acc*acc;
  for (int off=32; off; off>>=1) ss += __shfl_down(ss, off);
  if ((d & 63)==0) red2[d>>6] = ss;
  __syncthreads();
  float inv = 1.f/fmaxf(sqrtf(red2[0]+red2[1]), 1e-12f);
  srvb[(size_t)b*DD + d] = f2bf(FSCALE*acc*inv);
}

__global__ __launch_bounds__(256) void k_lse(const float* __restrict__ pmax, const float* __restrict__ psum,
                                             float* __restrict__ lse) {
  int r = blockIdx.x, tid = threadIdx.x;
  float m = -1e30f, s = 0.f;
  for (int cb = tid; cb < NCB; cb += 256) {
    float m2 = pmax[(size_t)r*NCB + cb], s2 = psum[(size_t)r*NCB + cb];
    float M = fmaxf(m, m2);
    s = s*expf(m - M) + s2*expf(m2 - M);
    m = M;
  }
  __shared__ float ms[256], ssh[256];
  ms[tid] = m; ssh[tid] = s; __syncthreads();
  for (int st=128; st; st>>=1) {
    if (tid < st) {
      float m2 = ms[tid+st], s2 = ssh[tid+st];
      float M = fmaxf(ms[tid], m2);
      ssh[tid] = ssh[tid]*expf(ms[tid]-M) + s2*expf(m2-M);
      ms[tid] = M;
    }
    __syncthreads();
  }
  if (tid==0) lse[r] = ms[0] + logf(ssh[0]);
}

extern "C" void kernel_launch(void* const* d_in, const int* in_sizes, int n_in,
                              void* d_out, int out_size, void* d_ws, size_t ws_size,
                              hipStream_t stream) {
  (void)in_sizes; (void)n_in; (void)out_size; (void)ws_size;
  const int*   iid    = (const int*)  d_in[0];
  const int*   src    = (const int*)  d_in[1];
  const int*   dst    = (const int*)  d_in[2];
  const float* edge_w = (const float*)d_in[3];
  const float* edge_t = (const float*)d_in[4];
  const float* node_t = (const float*)d_in[5];
  const float* emb    = (const float*)d_in[6];
  const float* W1     = (const float*)d_in[7];
  const float* W2     = (const float*)d_in[8];
  const float* gw_ih  = (const float*)d_in[9];
  const float* gw_hh  = (const float*)d_in[10];
  const float* gb_ih  = (const float*)d_in[11];
  const float* gb_hh  = (const float*)d_in[12];
  const float* Wxr = (const float*)d_in[13]; const float* bxr = (const float*)d_in[14];
  const float* Wxz = (const float*)d_in[15]; const float* bxz = (const float*)d_in[16];
  const float* Wxh = (const float*)d_in[17]; const float* bxh = (const float*)d_in[18];
  const float* Whr = (const float*)d_in[19]; const float* bhr = (const float*)d_in[20];
  const float* Whz = (const float*)d_in[21]; const float* bhz = (const float*)d_in[22];
  const float* Whh = (const float*)d_in[23]; const float* bhh = (const float*)d_in[24];
  const float* Wu  = (const float*)d_in[25];
  const float* Wv  = (const float*)d_in[26]; const float* bv  = (const float*)d_in[27];
  const float* We  = (const float*)d_in[28];
  const float* W_sr= (const float*)d_in[29];

  float* ws  = (float*)d_ws;
  float* out = (float*)d_out;

  // ---- workspace layout (float units; shorts live in float-sized slots) ----
  short* embn = (short*)ws;                         // VPAD*128 shorts = 6,402,048 fl
  float* pmax = ws + 6402048;                       // 512*1563 = 800,256
  float* psum = pmax + 800256;                      // 800,256
  short* M12t = (short*)(psum + 800256);            // 384*256 sh = 49,152 fl
  short* gwhhb= (short*)(psum + 800256 + 49152);    // 384*128 sh = 24,576 fl
  short* Wrzt = (short*)(psum + 800256 + 73728);    // 256*256 sh = 32,768 fl
  short* Wu2t = (short*)(psum + 800256 + 106496);   // 128*256 sh = 16,384 fl
  short* Wut  = (short*)(psum + 800256 + 122880);   // 128*128 sh = 8,192 fl
  short* Wvt  = (short*)(psum + 800256 + 131072);   // 8,192 fl
  float* brz  = psum + 800256 + 139264;             // 256
  float* bu   = brz + 256;                          // 128
  float* lv   = bu + 128;                           // 65,536
  float* dtp  = lv + 65536;                         // 4
  float* lse  = dtp + 4;                            // 512
  short* srvb = (short*)(lse + 512);                // 512*128 sh = 32,768 fl

  // ---- d_out as scratch until the logits pass (51.2M floats) ----
  short* ABb = (short*)out;                         // 25600*256 sh (3.28M fl)
  float* x   = out + (size_t) 4*1024*1024;          // 3.28M
  float* gi  = out + (size_t)20*1024*1024;          // 9.83M
  float* gh  = out + (size_t)30*1024*1024;          // 9.83M
  float* U   = out + (size_t)20*1024*1024;          // reuse gi after GRU
  short* xb  = (short*)(out + (size_t)40*1024*1024);// 25600*128 sh (1.64M fl)
  short* fbb = (short*)(out + (size_t)42*1024*1024);// 1.64M fl

  // ---- prep ----
  k_embn<<<VPAD/4, 256, 0, stream>>>(emb, embn);
  k_gather<<<NN, 128, 0, stream>>>(iid, emb, x, xb);
  k_dt<<<1, 256, 0, stream>>>(edge_t, dtp);
  k_m12t<<<384, 256, 0, stream>>>(W1, W2, gw_ih, M12t);
  k_bfcopy<<<384, 128, 0, stream>>>(gw_hh, gwhhb);
  k_wrzt<<<256, 256, 0, stream>>>(Wxr, Wxz, Whr, Whz, Wrzt);
  k_wu2t<<<128, 256, 0, stream>>>(Wxh, Whh, Wu2t);
  k_wt128<<<128, 128, 0, stream>>>(Wu, Wut);
  k_wt128<<<128, 128, 0, stream>>>(Wv, Wvt);
  k_build_bias<<<1, 384, 0, stream>>>(bxr, bhr, bxz, bhz, bxh, bhh, brz, bu);

  // ---- stage C (both directions, one kernel) ----
  k_grp_mean<<<BB, 256, 0, stream>>>(src, dst, edge_w, x, ABb);

  // ---- GRU ----
  gemm_mfma<<<dim3(6,400), 256, 0, stream>>>(ABb, 256, M12t, 256, gb_ih, gi, 384, 256, 0,
      nullptr, nullptr, nullptr);
  gemm_mfma<<<dim3(6,400), 256, 0, stream>>>(xb, 128, gwhhb, 128, gb_hh, gh, 384, 128, 0,
      nullptr, nullptr, nullptr);
  k_gru<<<NN, 128, 0, stream>>>(gi, gh, x);

  // ---- ODE (all 4 splits fused, per-group in LDS; outputs l2norm'd x + fbb) ----
  k_ode_fused<<<BB, 256, 0, stream>>>(src, dst, edge_t, node_t, dtp, x, fbb, Wrzt, Wu2t, brz, bu);

  // ---- attention ----
  gemm_mfma<<<dim3(2,400), 256, 0, stream>>>(fbb, 128, Wut, 128, nullptr, U, 128, 128, 0,
      nullptr, nullptr, nullptr);
  gemm_mfma<<<dim3(2,8), 256, 0, stream>>>(fbb + (size_t)(NPG-1)*DD, NPG*DD, Wvt, 128, bv, lv, 128, 128, 0,
      nullptr, nullptr, nullptr);
  k_attn<<<BB, 128, 0, stream>>>(x, U, lv, We, W_sr, srvb);

  // ---- logits: pass 1 (LSE partials) -> lse -> pass 2 (store acc - lse) ----
  gemm_mfma<<<dim3(8*NCB), 256, 0, stream>>>(srvb, 128, embn, 128, nullptr, nullptr, 0, 128, 4,
      nullptr, pmax, psum);
  k_lse<<<BB, 256, 0, stream>>>(pmax, psum, lse);
  gemm_mfma<<<dim3(8*NCB), 256, 0, stream>>>(srvb, 128, embn, 128, lse, nullptr, 0, 128, 5,
      out, nullptr, nullptr);
}